// Round 3
// baseline (748.201 us; speedup 1.0000x reference)
//
#include <hip/hip_runtime.h>
#include <stdint.h>

#define TOKENS 8192
#define KIN    4096
#define NOUT   11008

// ---- 256x256 8-phase GEMM geometry ----
#define BM 256
#define BN 256
#define BK 64
#define NT    (KIN / BK)      // 64 K-tiles
#define NTROW (TOKENS / BM)   // 32
#define NTCOL (NOUT / BN)     // 43
#define NWG   (NTROW * NTCOL) // 1376 (divisible by 8 -> simple XCD swizzle bijective)

using bf16x8 = __attribute__((ext_vector_type(8))) short;
using f32x4  = __attribute__((ext_vector_type(4))) float;

static __device__ __forceinline__ unsigned short f32_to_bf16(float f) {
  union { float f; uint32_t u; } v; v.f = f;
  uint32_t u = v.u;
  u += 0x7fffu + ((u >> 16) & 1u);   // round-to-nearest-even
  return (unsigned short)(u >> 16);
}

static __device__ __forceinline__ void gload_lds16(const void* g, void* l) {
  __builtin_amdgcn_global_load_lds((const __attribute__((address_space(1))) void*)g,
                                   (__attribute__((address_space(3))) void*)l,
                                   16, 0, 0);
}

// ---- kernel 1: per-row absmean quantization: Wq = bf16(round(W/scale)), scale[row] ----
__global__ __launch_bounds__(256) void quant_weight_k(const float* __restrict__ W,
                                                      unsigned short* __restrict__ Wq,
                                                      float* __restrict__ scale) {
  const int row = blockIdx.x;
  const int t   = threadIdx.x;
  const float4* wr = reinterpret_cast<const float4*>(W + (size_t)row * KIN);
  float4 v[4];
  double s = 0.0;
#pragma unroll
  for (int i = 0; i < 4; ++i) {
    v[i] = wr[t + i * 256];
    s += fabs((double)v[i].x) + fabs((double)v[i].y) +
         fabs((double)v[i].z) + fabs((double)v[i].w);
  }
#pragma unroll
  for (int off = 32; off > 0; off >>= 1) s += __shfl_down(s, off);
  __shared__ double red[4];
  if ((t & 63) == 0) red[t >> 6] = s;
  __syncthreads();
  const float sc = (float)((red[0] + red[1] + red[2] + red[3]) * (1.0 / KIN));
  if (t == 0) scale[row] = sc;
  ushort4* qr = reinterpret_cast<ushort4*>(Wq + (size_t)row * KIN);
#pragma unroll
  for (int i = 0; i < 4; ++i) {
    ushort4 q;
    q.x = f32_to_bf16(rintf(v[i].x / sc));
    q.y = f32_to_bf16(rintf(v[i].y / sc));
    q.z = f32_to_bf16(rintf(v[i].z / sc));
    q.w = f32_to_bf16(rintf(v[i].w / sc));
    qr[t + i * 256] = q;
  }
}

// ---- kernel 2: input fp32 -> bf16 ----
__global__ __launch_bounds__(256) void conv_input_k(const float* __restrict__ X,
                                                    unsigned short* __restrict__ Xb) {
  const int i = blockIdx.x * 256 + threadIdx.x;
  float4 v = reinterpret_cast<const float4*>(X)[i];
  ushort4 q;
  q.x = f32_to_bf16(v.x); q.y = f32_to_bf16(v.y);
  q.z = f32_to_bf16(v.z); q.w = f32_to_bf16(v.w);
  reinterpret_cast<ushort4*>(Xb)[i] = q;
}

// ---- kernel 3: 256x256x64 8-phase pipelined GEMM (T1+T2+T3+T4+T5) ----
// C[t,o] = scale[o]*(Xb[t,:].Wq[o,:]) + bias[o].  Both operands row-major [row][K].
//
// LDS map (128 KiB): A: [buf][256 rows][64 bf16] at 0 + buf*32768
//                    B: same at 65536 + buf*32768
// st-swizzle: LDS linear (row, c) holds global (row, c ^ ((row&7)<<4)); applied by
// pre-swizzling the global source lane address (global_load_lds dest must be linear)
// and XOR-ing the same pattern into every ds_read address.
//
// Deep-prefetch schedule per K-tile t (cur = t&1), staging tile t+2 into cur:
//  ph0: ds_read A m0-3 (8) + B n0-1 (4);                      MFMA m0-3 x n0-1
//  ph1: ds_read B n2-3 (4);                                   MFMA m0-3 x n2-3
//  ph2: ds_read A m4-7 (8); stage B(t+2)h0,h1 -> cur;         MFMA m4-7 x n2-3
//       (legal: B-cur's last ds_read is ph1, drained by ph1's lgkmcnt+barrier)
//  ph3: stage A(t+2)h0,h1 -> cur;                             MFMA m4-7 x n0-1
//       (legal: A-cur's last ds_read is ph2, drained by ph2's lgkmcnt+barrier)
//       then s_waitcnt vmcnt(8) — the 8 t+2 loads stay in flight; everything
//       older (tile t+1's 8 loads, issued during t-1) is confirmed landed.
// Prefetch distance: 4 phases (~700+ cyc) vs ~2-3 before — covers HBM-miss latency.
__global__ __launch_bounds__(512, 2) void gemm_k(const unsigned short* __restrict__ Xb,
                                                 const unsigned short* __restrict__ Wq,
                                                 const float* __restrict__ scale,
                                                 const float* __restrict__ bias,
                                                 float* __restrict__ out) {
  __shared__ alignas(16) char lds[131072];

  // T1: XCD-aware swizzle (1376 % 8 == 0 -> bijective)
  int bid = (int)blockIdx.x;
  bid = (bid & 7) * (NWG / 8) + (bid >> 3);
  const int trow = bid / NTCOL;
  const int tcol = bid % NTCOL;

  const int tid  = (int)threadIdx.x;
  const int lane = tid & 63;
  const int wave = tid >> 6;   // 0..7
  const int wm   = wave >> 2;  // 0..1 : M half (128 rows)
  const int wn   = wave & 3;   // 0..3 : N quarter (64 cols)

  // ---- staging lane addresses (inverse-swizzled global source, linear LDS dest) ----
  const int l8 = lane >> 3;                          // 0..7 -> row within 8-row group
  const size_t rowb = (size_t)KIN * 2;               // 8192 B per row
  const int swzl = ((lane & 7) ^ l8) * 16;           // pre-swizzled k-byte within 128B slice
  const char* gA = (const char*)Xb + (size_t)(trow * BM + wave * 16 + l8) * rowb + swzl;
  const char* gB = (const char*)Wq + (size_t)(tcol * BN + wave * 16 + l8) * rowb + swzl;
  char* lA = lds + wave * 2048;            // + buf*32768 + h*16384 (+1024 for 2nd load)
  char* lB = lds + 65536 + wave * 2048;

#define STAGE(gp, lp, koff) do {                                             \
    gload_lds16((gp) + (koff), (lp));                                        \
    gload_lds16((gp) + (koff) + (size_t)65536, (char*)(lp) + 1024);          \
  } while (0)

  // ---- ds_read bases (swizzled) ----
  const int lr = lane & 15;
  const int hi = lane >> 4;
  const int swz0 = (hi * 16) ^ ((lr & 7) << 4);
  const int swz[2] = { swz0, swz0 ^ 64 };            // kk=0 / kk=1 (XOR, not add: bit6 overlaps)
  const char* rdA = lds + wm * 16384 + lr * 128;
  const char* rdB = lds + 65536 + (wn >> 1) * 16384 + ((wn & 1) * 64 + lr) * 128;

  f32x4 acc[8][4];
#pragma unroll
  for (int m = 0; m < 8; ++m)
#pragma unroll
    for (int n = 0; n < 4; ++n) acc[m][n] = (f32x4){0.f, 0.f, 0.f, 0.f};
  bf16x8 afr[4][2], bfr[4][2];

#define LDA(mf, mbase, kk) afr[mf][kk] = *(const bf16x8*)(rdA + cur + ((mbase) + (mf)) * 2048 + swz[kk])
#define LDB(nf, kk)        bfr[nf][kk] = *(const bf16x8*)(rdB + cur + (nf) * 2048 + swz[kk])

#define QUAD(MB, NB)                                                          \
    _Pragma("unroll") for (int mf = 0; mf < 4; ++mf)                          \
    _Pragma("unroll") for (int nf = 0; nf < 2; ++nf)                          \
    _Pragma("unroll") for (int kk = 0; kk < 2; ++kk)                          \
      acc[(MB) + mf][(NB) + nf] = __builtin_amdgcn_mfma_f32_16x16x32_bf16(    \
          afr[mf][kk], bfr[(NB) + nf][kk], acc[(MB) + mf][(NB) + nf], 0, 0, 0)

#define PHASE_MID()                                         \
    __builtin_amdgcn_s_barrier();                           \
    asm volatile("s_waitcnt lgkmcnt(0)" ::: "memory");      \
    __builtin_amdgcn_sched_barrier(0);                      \
    __builtin_amdgcn_s_setprio(1)

#define PHASE_END()                                         \
    __builtin_amdgcn_s_setprio(0);                          \
    __builtin_amdgcn_s_barrier()

  // ---- prologue: stage tiles 0 and 1 fully (16 loads); wait tile0 (vmcnt(8)) ----
  STAGE(gA,              lA,                 0);    // A(0) h0
  STAGE(gA + 128 * rowb, lA + 16384,         0);    // A(0) h1
  STAGE(gB,              lB,                 0);    // B(0) h0
  STAGE(gB + 128 * rowb, lB + 16384,         0);    // B(0) h1
  STAGE(gA,              lA + 32768,         128);  // A(1) h0
  STAGE(gA + 128 * rowb, lA + 32768 + 16384, 128);  // A(1) h1
  STAGE(gB,              lB + 32768,         128);  // B(1) h0
  STAGE(gB + 128 * rowb, lB + 32768 + 16384, 128);  // B(1) h1
  asm volatile("s_waitcnt vmcnt(8)" ::: "memory");  // tile0 landed; tile1 in flight
  __builtin_amdgcn_s_barrier();

#pragma unroll 2
  for (int t = 0; t < NT; ++t) {
    const int cur = (t & 1) * 32768;
    const size_t kN = (size_t)(t + 2) * 128;   // byte offset of K-tile t+2

    // ---------- phase 0 ----------
    __builtin_amdgcn_sched_barrier(0);
#pragma unroll
    for (int mf = 0; mf < 4; ++mf) { LDA(mf, 0, 0); LDA(mf, 0, 1); }
#pragma unroll
    for (int nf = 0; nf < 2; ++nf) { LDB(nf, 0); LDB(nf, 1); }
    PHASE_MID();
    QUAD(0, 0);
    PHASE_END();

    // ---------- phase 1 ----------
    __builtin_amdgcn_sched_barrier(0);
#pragma unroll
    for (int nf = 2; nf < 4; ++nf) { LDB(nf, 0); LDB(nf, 1); }
    PHASE_MID();
    QUAD(0, 2);
    PHASE_END();

    // ---------- phase 2 ----------
    __builtin_amdgcn_sched_barrier(0);
#pragma unroll
    for (int mf = 0; mf < 4; ++mf) { LDA(mf, 4, 0); LDA(mf, 4, 1); }
    if (t + 2 < NT) {                                   // B(t+2) -> cur (B-cur reads done after ph1)
      STAGE(gB, lB + cur, kN);
      STAGE(gB + 128 * rowb, lB + cur + 16384, kN);
    }
    PHASE_MID();
    QUAD(4, 2);
    PHASE_END();

    // ---------- phase 3 ----------
    __builtin_amdgcn_sched_barrier(0);
    if (t + 2 < NT) {                                   // A(t+2) -> cur (A-cur reads done after ph2)
      STAGE(gA, lA + cur, kN);
      STAGE(gA + 128 * rowb, lA + cur + 16384, kN);
    }
    PHASE_MID();
    QUAD(4, 0);
    __builtin_amdgcn_s_setprio(0);
    if (t < NT - 2) { asm volatile("s_waitcnt vmcnt(8)" ::: "memory"); }  // counted, never 0
    else           { asm volatile("s_waitcnt vmcnt(0)" ::: "memory"); }  // epilogue drain
    __builtin_amdgcn_s_barrier();
  }

  // ---- epilogue: C/D layout col = lane&15, row = (lane>>4)*4 + reg ----
  // Nontemporal stores: output is write-once; bypass L2/L3 so the 150 MB operand
  // set stays cache-resident for other blocks (cuts HBM FETCH + stage latency).
  const int gr_base = trow * BM + wm * 128 + hi * 4;
  const int gc_base = tcol * BN + wn * 64 + lr;
#pragma unroll
  for (int nf = 0; nf < 4; ++nf) {
    const int gc = gc_base + nf * 16;
    const float s  = scale[gc];
    const float bb = bias[gc];
#pragma unroll
    for (int mf = 0; mf < 8; ++mf) {
      const size_t rb = (size_t)(gr_base + mf * 16) * NOUT + gc;
#pragma unroll
      for (int j = 0; j < 4; ++j)
        __builtin_nontemporal_store(acc[mf][nf][j] * s + bb, &out[rb + (size_t)j * NOUT]);
    }
  }
#undef STAGE
#undef LDA
#undef LDB
#undef QUAD
#undef PHASE_MID
#undef PHASE_END
}

extern "C" void kernel_launch(void* const* d_in, const int* in_sizes, int n_in,
                              void* d_out, int out_size, void* d_ws, size_t ws_size,
                              hipStream_t stream) {
  const float* X  = (const float*)d_in[0];   // [8192, 4096] fp32
  const float* W  = (const float*)d_in[1];   // [11008, 4096] fp32
  const float* Bi = (const float*)d_in[2];   // [11008] fp32
  float* out = (float*)d_out;                // [8192, 11008] fp32

  const size_t xb_bytes = (size_t)TOKENS * KIN * 2;  // 64 MiB
  const size_t wq_bytes = (size_t)NOUT * KIN * 2;    // 86 MiB
  const size_t need = xb_bytes + wq_bytes + (size_t)NOUT * sizeof(float);
  if (ws_size < need) return;  // needs ~157.3 MB scratch

  char* ws = (char*)d_ws;
  unsigned short* Xb = (unsigned short*)ws;
  unsigned short* Wq = (unsigned short*)(ws + xb_bytes);
  float* scale = (float*)(ws + xb_bytes + wq_bytes);

  quant_weight_k<<<NOUT, 256, 0, stream>>>(W, Wq, scale);
  conv_input_k<<<(TOKENS * KIN / 4) / 256, 256, 0, stream>>>(X, Xb);
  gemm_k<<<NWG, 512, 0, stream>>>(Xb, Wq, scale, Bi, out);
}

// Round 4
// 469.165 us; speedup vs baseline: 1.5948x; 1.5948x over previous
//
#include <hip/hip_runtime.h>
#include <stdint.h>

#define TOKENS 8192
#define KIN    4096
#define NOUT   11008

// ---- 256x256 8-phase GEMM geometry (i8, BK=128 => 128 B/row, same LDS map as bf16 BK=64) ----
#define BM 256
#define BN 256
#define BK 128
#define NT    (KIN / BK)      // 32 K-tiles
#define NTROW (TOKENS / BM)   // 32
#define NTCOL (NOUT / BN)     // 43
#define NWG   (NTROW * NTCOL) // 1376 (divisible by 8 -> simple XCD swizzle bijective)

using i32x4 = __attribute__((ext_vector_type(4))) int;

static __device__ __forceinline__ void gload_lds16(const void* g, void* l) {
  __builtin_amdgcn_global_load_lds((const __attribute__((address_space(1))) void*)g,
                                   (__attribute__((address_space(3))) void*)l,
                                   16, 0, 0);
}

static __device__ __forceinline__ int clamp_q(float f) {
  int q = (int)rintf(f);
  q = q > 127 ? 127 : q;
  q = q < -127 ? -127 : q;
  return q;
}

static __device__ __forceinline__ int pack4(int a, int b, int c, int d) {
  return (a & 0xff) | ((b & 0xff) << 8) | ((c & 0xff) << 16) | ((d & 0xff) << 24);
}

// ---- kernel 1: per-row absmean quantization: Wq = i8(round(W/scale)), scale_w[row] ----
// scale via f64 reduction (matches round-boundary behavior of the passing bf16 version).
__global__ __launch_bounds__(256) void quant_weight_k(const float* __restrict__ W,
                                                      signed char* __restrict__ Wq,
                                                      float* __restrict__ scale_w) {
  const int row = blockIdx.x;
  const int t   = threadIdx.x;
  const float4* wr = reinterpret_cast<const float4*>(W + (size_t)row * KIN);
  float4 v[4];
  double s = 0.0;
#pragma unroll
  for (int i = 0; i < 4; ++i) {
    v[i] = wr[t + i * 256];
    s += fabs((double)v[i].x) + fabs((double)v[i].y) +
         fabs((double)v[i].z) + fabs((double)v[i].w);
  }
#pragma unroll
  for (int off = 32; off > 0; off >>= 1) s += __shfl_down(s, off);
  __shared__ double red[4];
  if ((t & 63) == 0) red[t >> 6] = s;
  __syncthreads();
  const float sc = (float)((red[0] + red[1] + red[2] + red[3]) * (1.0 / KIN));
  if (t == 0) scale_w[row] = sc;
  int* qr = reinterpret_cast<int*>(Wq + (size_t)row * KIN);
#pragma unroll
  for (int i = 0; i < 4; ++i) {
    qr[t + i * 256] = pack4(clamp_q(v[i].x / sc), clamp_q(v[i].y / sc),
                            clamp_q(v[i].z / sc), clamp_q(v[i].w / sc));
  }
}

// ---- kernel 2: per-token symmetric i8 quantization of x: s_x = absmax/127 ----
__global__ __launch_bounds__(256) void quant_input_k(const float* __restrict__ X,
                                                     signed char* __restrict__ Xq,
                                                     float* __restrict__ scale_x) {
  const int row = blockIdx.x;
  const int t   = threadIdx.x;
  const float4* xr = reinterpret_cast<const float4*>(X + (size_t)row * KIN);
  float4 v[4];
  float amax = 0.f;
#pragma unroll
  for (int i = 0; i < 4; ++i) {
    v[i] = xr[t + i * 256];
    amax = fmaxf(amax, fmaxf(fmaxf(fabsf(v[i].x), fabsf(v[i].y)),
                             fmaxf(fabsf(v[i].z), fabsf(v[i].w))));
  }
#pragma unroll
  for (int off = 32; off > 0; off >>= 1) amax = fmaxf(amax, __shfl_down(amax, off));
  __shared__ float red[4];
  if ((t & 63) == 0) red[t >> 6] = amax;
  __syncthreads();
  amax = fmaxf(fmaxf(red[0], red[1]), fmaxf(red[2], red[3]));
  amax = fmaxf(amax, 1e-30f);
  const float inv = 127.0f / amax;
  if (t == 0) scale_x[row] = amax * (1.0f / 127.0f);
  int* qr = reinterpret_cast<int*>(Xq + (size_t)row * KIN);
#pragma unroll
  for (int i = 0; i < 4; ++i) {
    qr[t + i * 256] = pack4(clamp_q(v[i].x * inv), clamp_q(v[i].y * inv),
                            clamp_q(v[i].z * inv), clamp_q(v[i].w * inv));
  }
}

// ---- kernel 3: 256x256x128 i8 8-phase pipelined GEMM (T1+T2+T3+T4+T5) ----
// out[t,o] = s_x[t]*s_w[o]*(Xq[t,:].Wq[o,:])_i32 + bias[o].  Row-major [row][K] i8.
//
// LDS map (128 KiB): A: [buf][256 rows][128 B] at 0 + buf*32768; B at 65536 + buf*32768.
// Byte-identical geometry to the bf16 BK=64 version (i8 BK=128 = 128 B/row).
// Swizzle: LDS slot c (16 B) of row r holds global slot c ^ (r&7); applied by
// pre-swizzling the global source lane address (linear gload_lds dest) and XOR on reads.
//
// MFMA: mfma_i32_16x16x64_i8. Lane l holds row/col (l&15), k = (l>>4)*16 + 0..15
// (16 contiguous K-bytes per lane = one 16-B slot => same ds_read math as bf16).
// Per K-tile: 2 k-slices (ks=0/1, bytes ks*64) x 8 m x 4 n = 64 MFMA/wave, 16/phase.
//
// Deep-prefetch schedule per K-tile t (cur = t&1), staging tile t+2 into cur:
//  ph0: ds_read A m0-3 (8) + B n0-1 (4);                 MFMA m0-3 x n0-1
//  ph1: ds_read B n2-3 (4);                              MFMA m0-3 x n2-3
//  ph2: ds_read A m4-7 (8); stage B(t+2) -> cur;         MFMA m4-7 x n2-3
//  ph3: stage A(t+2) -> cur;                             MFMA m4-7 x n0-1
//       then s_waitcnt vmcnt(8) (counted; drain only in last 2 tiles).
__global__ __launch_bounds__(512, 2) void gemm_k(const signed char* __restrict__ Xq,
                                                 const signed char* __restrict__ Wq,
                                                 const float* __restrict__ scale_x,
                                                 const float* __restrict__ scale_w,
                                                 const float* __restrict__ bias,
                                                 float* __restrict__ out) {
  __shared__ alignas(16) char lds[131072];

  // T1: XCD-aware swizzle (1376 % 8 == 0 -> bijective)
  int bid = (int)blockIdx.x;
  bid = (bid & 7) * (NWG / 8) + (bid >> 3);
  const int trow = bid / NTCOL;
  const int tcol = bid % NTCOL;

  const int tid  = (int)threadIdx.x;
  const int lane = tid & 63;
  const int wave = tid >> 6;   // 0..7
  const int wm   = wave >> 2;  // 0..1 : M half (128 rows)
  const int wn   = wave & 3;   // 0..3 : N quarter (64 cols)

  // ---- staging lane addresses (inverse-swizzled global source, linear LDS dest) ----
  const int l8 = lane >> 3;                          // row within 8-row group
  const size_t rowb = (size_t)KIN;                   // 4096 B per row (i8)
  const int swzl = ((lane & 7) ^ l8) * 16;           // pre-swizzled slot within 128-B row chunk
  const char* gA = (const char*)Xq + (size_t)(trow * BM + wave * 16 + l8) * rowb + swzl;
  const char* gB = (const char*)Wq + (size_t)(tcol * BN + wave * 16 + l8) * rowb + swzl;
  char* lA = lds + wave * 2048;            // + buf*32768 + h*16384 (+1024 for 2nd gload)
  char* lB = lds + 65536 + wave * 2048;

#define STAGE(gp, lp, koff) do {                                             \
    gload_lds16((gp) + (koff), (lp));                                        \
    gload_lds16((gp) + (koff) + (size_t)(8 * 4096), (char*)(lp) + 1024);     \
  } while (0)

  // ---- ds_read bases (swizzled) ----
  const int lr = lane & 15;
  const int hi = lane >> 4;                          // 0..3 -> k-slot within 64-B k-slice
  const int swz0 = (hi * 16) ^ ((lr & 7) << 4);
  const int swz[2] = { swz0, swz0 ^ 64 };            // ks=0 / ks=1 (XOR: bit6 overlaps swizzle field)
  const char* rdA = lds + wm * 16384 + lr * 128;
  const char* rdB = lds + 65536 + (wn >> 1) * 16384 + ((wn & 1) * 64 + lr) * 128;

  i32x4 acc[8][4];
#pragma unroll
  for (int m = 0; m < 8; ++m)
#pragma unroll
    for (int n = 0; n < 4; ++n) acc[m][n] = (i32x4){0, 0, 0, 0};
  i32x4 afr[4][2], bfr[4][2];

#define LDA(mf, mbase, kk) afr[mf][kk] = *(const i32x4*)(rdA + cur + ((mbase) + (mf)) * 2048 + swz[kk])
#define LDB(nf, kk)        bfr[nf][kk] = *(const i32x4*)(rdB + cur + (nf) * 2048 + swz[kk])

#define QUAD(MB, NB)                                                          \
    _Pragma("unroll") for (int mf = 0; mf < 4; ++mf)                          \
    _Pragma("unroll") for (int nf = 0; nf < 2; ++nf)                          \
    _Pragma("unroll") for (int kk = 0; kk < 2; ++kk)                          \
      acc[(MB) + mf][(NB) + nf] = __builtin_amdgcn_mfma_i32_16x16x64_i8(      \
          afr[mf][kk], bfr[(NB) + nf][kk], acc[(MB) + mf][(NB) + nf], 0, 0, 0)

#define PHASE_MID()                                         \
    __builtin_amdgcn_s_barrier();                           \
    asm volatile("s_waitcnt lgkmcnt(0)" ::: "memory");      \
    __builtin_amdgcn_sched_barrier(0);                      \
    __builtin_amdgcn_s_setprio(1)

#define PHASE_END()                                         \
    __builtin_amdgcn_s_setprio(0);                          \
    __builtin_amdgcn_s_barrier()

  // ---- prologue: stage tiles 0 and 1 fully (16 loads); wait tile0 (vmcnt(8)) ----
  STAGE(gA,              lA,                 0);    // A(0) h0
  STAGE(gA + 128 * rowb, lA + 16384,         0);    // A(0) h1
  STAGE(gB,              lB,                 0);    // B(0) h0
  STAGE(gB + 128 * rowb, lB + 16384,         0);    // B(0) h1
  STAGE(gA,              lA + 32768,         128);  // A(1) h0
  STAGE(gA + 128 * rowb, lA + 32768 + 16384, 128);  // A(1) h1
  STAGE(gB,              lB + 32768,         128);  // B(1) h0
  STAGE(gB + 128 * rowb, lB + 32768 + 16384, 128);  // B(1) h1
  asm volatile("s_waitcnt vmcnt(8)" ::: "memory");  // tile0 landed; tile1 in flight
  __builtin_amdgcn_s_barrier();

#pragma unroll 2
  for (int t = 0; t < NT; ++t) {
    const int cur = (t & 1) * 32768;
    const size_t kN = (size_t)(t + 2) * 128;   // byte offset of K-tile t+2 (BK=128 i8)

    // ---------- phase 0 ----------
    __builtin_amdgcn_sched_barrier(0);
#pragma unroll
    for (int mf = 0; mf < 4; ++mf) { LDA(mf, 0, 0); LDA(mf, 0, 1); }
#pragma unroll
    for (int nf = 0; nf < 2; ++nf) { LDB(nf, 0); LDB(nf, 1); }
    PHASE_MID();
    QUAD(0, 0);
    PHASE_END();

    // ---------- phase 1 ----------
    __builtin_amdgcn_sched_barrier(0);
#pragma unroll
    for (int nf = 2; nf < 4; ++nf) { LDB(nf, 0); LDB(nf, 1); }
    PHASE_MID();
    QUAD(0, 2);
    PHASE_END();

    // ---------- phase 2 ----------
    __builtin_amdgcn_sched_barrier(0);
#pragma unroll
    for (int mf = 0; mf < 4; ++mf) { LDA(mf, 4, 0); LDA(mf, 4, 1); }
    if (t + 2 < NT) {                                   // B(t+2) -> cur (B-cur reads done after ph1)
      STAGE(gB, lB + cur, kN);
      STAGE(gB + 128 * rowb, lB + cur + 16384, kN);
    }
    PHASE_MID();
    QUAD(4, 2);
    PHASE_END();

    // ---------- phase 3 ----------
    __builtin_amdgcn_sched_barrier(0);
    if (t + 2 < NT) {                                   // A(t+2) -> cur (A-cur reads done after ph2)
      STAGE(gA, lA + cur, kN);
      STAGE(gA + 128 * rowb, lA + cur + 16384, kN);
    }
    PHASE_MID();
    QUAD(4, 0);
    __builtin_amdgcn_s_setprio(0);
    if (t < NT - 2) { asm volatile("s_waitcnt vmcnt(8)" ::: "memory"); }  // counted, never 0
    else           { asm volatile("s_waitcnt vmcnt(0)" ::: "memory"); }  // epilogue drain
    __builtin_amdgcn_s_barrier();
  }

  // ---- epilogue: C/D layout col = lane&15, row = (lane>>4)*4 + reg (dtype-independent) ----
  const int gr_base = trow * BM + wm * 128 + hi * 4;
  const int gc_base = tcol * BN + wn * 64 + lr;
  float sx[8][4];
#pragma unroll
  for (int mf = 0; mf < 8; ++mf)
#pragma unroll
    for (int j = 0; j < 4; ++j) sx[mf][j] = scale_x[gr_base + mf * 16 + j];
#pragma unroll
  for (int nf = 0; nf < 4; ++nf) {
    const int gc = gc_base + nf * 16;
    const float sw = scale_w[gc];
    const float bb = bias[gc];
#pragma unroll
    for (int mf = 0; mf < 8; ++mf) {
      const size_t rb = (size_t)(gr_base + mf * 16) * NOUT + gc;
#pragma unroll
      for (int j = 0; j < 4; ++j)
        out[rb + (size_t)j * NOUT] = (float)acc[mf][nf][j] * (sx[mf][j] * sw) + bb;
    }
  }
#undef STAGE
#undef LDA
#undef LDB
#undef QUAD
#undef PHASE_MID
#undef PHASE_END
}

extern "C" void kernel_launch(void* const* d_in, const int* in_sizes, int n_in,
                              void* d_out, int out_size, void* d_ws, size_t ws_size,
                              hipStream_t stream) {
  const float* X  = (const float*)d_in[0];   // [8192, 4096] fp32
  const float* W  = (const float*)d_in[1];   // [11008, 4096] fp32
  const float* Bi = (const float*)d_in[2];   // [11008] fp32
  float* out = (float*)d_out;                // [8192, 11008] fp32

  const size_t xq_bytes = (size_t)TOKENS * KIN;      // 32 MiB
  const size_t wq_bytes = (size_t)NOUT * KIN;        // 43 MiB
  const size_t need = xq_bytes + wq_bytes + (size_t)(NOUT + TOKENS) * sizeof(float);
  if (ws_size < need) return;  // needs ~76 MB scratch

  char* ws = (char*)d_ws;
  signed char* Xq = (signed char*)ws;
  signed char* Wq = (signed char*)(ws + xq_bytes);
  float* scale_w = (float*)(ws + xq_bytes + wq_bytes);
  float* scale_x = scale_w + NOUT;

  quant_weight_k<<<NOUT, 256, 0, stream>>>(W, Wq, scale_w);
  quant_input_k<<<TOKENS, 256, 0, stream>>>(X, Xq, scale_x);
  gemm_k<<<NWG, 512, 0, stream>>>(Xq, Wq, scale_x, scale_w, Bi, out);
}

// Round 5
// 465.463 us; speedup vs baseline: 1.6074x; 1.0080x over previous
//
#include <hip/hip_runtime.h>
#include <stdint.h>

#define TOKENS 8192
#define KIN    4096
#define NOUT   11008

// ---- 256x256 8-phase GEMM geometry (i8, BK=128 => 128 B/row, same LDS map as bf16 BK=64) ----
#define BM 256
#define BN 256
#define BK 128
#define NT    (KIN / BK)      // 32 K-tiles
#define NTROW (TOKENS / BM)   // 32
#define NTCOL (NOUT / BN)     // 43
#define NWG   (NTROW * NTCOL) // 1376 (divisible by 8 -> simple XCD swizzle bijective)

using i32x4 = __attribute__((ext_vector_type(4))) int;

static __device__ __forceinline__ void gload_lds16(const void* g, void* l) {
  __builtin_amdgcn_global_load_lds((const __attribute__((address_space(1))) void*)g,
                                   (__attribute__((address_space(3))) void*)l,
                                   16, 0, 0);
}

static __device__ __forceinline__ int clamp_q(float f) {
  int q = (int)rintf(f);
  q = q > 127 ? 127 : q;
  q = q < -127 ? -127 : q;
  return q;
}

static __device__ __forceinline__ int pack4(int a, int b, int c, int d) {
  return (a & 0xff) | ((b & 0xff) << 8) | ((c & 0xff) << 16) | ((d & 0xff) << 24);
}

// ---- kernel 1: per-row absmean quantization: Wq = i8(round(W/scale)), scale_w[row] ----
__global__ __launch_bounds__(256) void quant_weight_k(const float* __restrict__ W,
                                                      signed char* __restrict__ Wq,
                                                      float* __restrict__ scale_w) {
  const int row = blockIdx.x;
  const int t   = threadIdx.x;
  const float4* wr = reinterpret_cast<const float4*>(W + (size_t)row * KIN);
  float4 v[4];
  double s = 0.0;
#pragma unroll
  for (int i = 0; i < 4; ++i) {
    v[i] = wr[t + i * 256];
    s += fabs((double)v[i].x) + fabs((double)v[i].y) +
         fabs((double)v[i].z) + fabs((double)v[i].w);
  }
#pragma unroll
  for (int off = 32; off > 0; off >>= 1) s += __shfl_down(s, off);
  __shared__ double red[4];
  if ((t & 63) == 0) red[t >> 6] = s;
  __syncthreads();
  const float sc = (float)((red[0] + red[1] + red[2] + red[3]) * (1.0 / KIN));
  if (t == 0) scale_w[row] = sc;
  int* qr = reinterpret_cast<int*>(Wq + (size_t)row * KIN);
#pragma unroll
  for (int i = 0; i < 4; ++i) {
    qr[t + i * 256] = pack4(clamp_q(v[i].x / sc), clamp_q(v[i].y / sc),
                            clamp_q(v[i].z / sc), clamp_q(v[i].w / sc));
  }
}

// ---- kernel 2: per-token symmetric i8 quantization of x: s_x = absmax/127 ----
__global__ __launch_bounds__(256) void quant_input_k(const float* __restrict__ X,
                                                     signed char* __restrict__ Xq,
                                                     float* __restrict__ scale_x) {
  const int row = blockIdx.x;
  const int t   = threadIdx.x;
  const float4* xr = reinterpret_cast<const float4*>(X + (size_t)row * KIN);
  float4 v[4];
  float amax = 0.f;
#pragma unroll
  for (int i = 0; i < 4; ++i) {
    v[i] = xr[t + i * 256];
    amax = fmaxf(amax, fmaxf(fmaxf(fabsf(v[i].x), fabsf(v[i].y)),
                             fmaxf(fabsf(v[i].z), fabsf(v[i].w))));
  }
#pragma unroll
  for (int off = 32; off > 0; off >>= 1) amax = fmaxf(amax, __shfl_down(amax, off));
  __shared__ float red[4];
  if ((t & 63) == 0) red[t >> 6] = amax;
  __syncthreads();
  amax = fmaxf(fmaxf(red[0], red[1]), fmaxf(red[2], red[3]));
  amax = fmaxf(amax, 1e-30f);
  const float inv = 127.0f / amax;
  if (t == 0) scale_x[row] = amax * (1.0f / 127.0f);
  int* qr = reinterpret_cast<int*>(Xq + (size_t)row * KIN);
#pragma unroll
  for (int i = 0; i < 4; ++i) {
    qr[t + i * 256] = pack4(clamp_q(v[i].x * inv), clamp_q(v[i].y * inv),
                            clamp_q(v[i].z * inv), clamp_q(v[i].w * inv));
  }
}

// ---- kernel 3: 256x256x128 i8 8-phase pipelined GEMM ----
// out[t,o] = s_x[t]*s_w[o]*(Xq[t,:].Wq[o,:])_i32 + bias[o].  Row-major [row][K] i8.
//
// LDS map (128 KiB): A: [buf][256 rows][128 B] at 0 + buf*32768; B at 65536 + buf*32768.
// Swizzle: LDS slot c (16 B) of row r holds global slot c ^ (r&7); applied by
// pre-swizzling the global source lane address (linear gload_lds dest) and XOR on reads.
//
// R5 change: NO blanket lgkmcnt(0) before the MFMA cluster. All ds_reads are
// compiler-visible, so hipcc inserts fine-grained lgkmcnt(N) per consuming MFMA —
// early MFMAs execute while later reads drain (LDS pipe || MFMA pipe overlap).
// Overwrite safety still holds: every read is consumed by an in-phase MFMA
// (phase-top sched_barrier(0) pins instructions to their phase), so a wave's
// reads are complete before it reaches the phase-end s_barrier; stages that
// overwrite a slot issue >= 1 barrier-pair after the slot's last read phase.
//
// Schedule per K-tile t (cur = t&1), staging tile t+2 into cur:
//  ph0: ds_read A m0-3 (8) + B n0-1 (4);                 MFMA m0-3 x n0-1
//  ph1: ds_read B n2-3 (4);                              MFMA m0-3 x n2-3
//  ph2: stage B(t+2) -> cur; ds_read A m4-7 (8);         MFMA m4-7 x n2-3
//       (B-cur's last reads ph1, drained at ph1-end barrier)
//  ph3: stage A(t+2) -> cur;                             MFMA m4-7 x n0-1
//       (A-cur's last reads ph2, drained at ph2-end barrier)
//       then s_waitcnt vmcnt(8) (counted; drain only in last 2 tiles).
__global__ __launch_bounds__(512, 2) void gemm_k(const signed char* __restrict__ Xq,
                                                 const signed char* __restrict__ Wq,
                                                 const float* __restrict__ scale_x,
                                                 const float* __restrict__ scale_w,
                                                 const float* __restrict__ bias,
                                                 float* __restrict__ out) {
  __shared__ alignas(16) char lds[131072];

  // T1: XCD-aware swizzle (1376 % 8 == 0 -> bijective)
  int bid = (int)blockIdx.x;
  bid = (bid & 7) * (NWG / 8) + (bid >> 3);
  const int trow = bid / NTCOL;
  const int tcol = bid % NTCOL;

  const int tid  = (int)threadIdx.x;
  const int lane = tid & 63;
  const int wave = tid >> 6;   // 0..7
  const int wm   = wave >> 2;  // 0..1 : M half (128 rows)
  const int wn   = wave & 3;   // 0..3 : N quarter (64 cols)

  // ---- staging lane addresses (inverse-swizzled global source, linear LDS dest) ----
  const int l8 = lane >> 3;                          // row within 8-row group
  const size_t rowb = (size_t)KIN;                   // 4096 B per row (i8)
  const int swzl = ((lane & 7) ^ l8) * 16;           // pre-swizzled slot within 128-B row chunk
  const char* gA = (const char*)Xq + (size_t)(trow * BM + wave * 16 + l8) * rowb + swzl;
  const char* gB = (const char*)Wq + (size_t)(tcol * BN + wave * 16 + l8) * rowb + swzl;
  char* lA = lds + wave * 2048;            // + buf*32768 + h*16384 (+1024 for 2nd gload)
  char* lB = lds + 65536 + wave * 2048;

#define STAGE(gp, lp, koff) do {                                             \
    gload_lds16((gp) + (koff), (lp));                                        \
    gload_lds16((gp) + (koff) + (size_t)(8 * 4096), (char*)(lp) + 1024);     \
  } while (0)

  // ---- ds_read bases (swizzled) ----
  const int lr = lane & 15;
  const int hi = lane >> 4;                          // 0..3 -> k-slot within 64-B k-slice
  const int swz0 = (hi * 16) ^ ((lr & 7) << 4);
  const int swz[2] = { swz0, swz0 ^ 64 };            // ks=0 / ks=1 (XOR: bit6 overlaps swizzle field)
  const char* rdA = lds + wm * 16384 + lr * 128;
  const char* rdB = lds + 65536 + (wn >> 1) * 16384 + ((wn & 1) * 64 + lr) * 128;

  i32x4 acc[8][4];
#pragma unroll
  for (int m = 0; m < 8; ++m)
#pragma unroll
    for (int n = 0; n < 4; ++n) acc[m][n] = (i32x4){0, 0, 0, 0};
  i32x4 afr[4][2], bfr[4][2];

#define LDA(mf, mbase, kk) afr[mf][kk] = *(const i32x4*)(rdA + cur + ((mbase) + (mf)) * 2048 + swz[kk])
#define LDB(nf, kk)        bfr[nf][kk] = *(const i32x4*)(rdB + cur + (nf) * 2048 + swz[kk])

#define QUAD(MB, NB)                                                          \
    _Pragma("unroll") for (int mf = 0; mf < 4; ++mf)                          \
    _Pragma("unroll") for (int nf = 0; nf < 2; ++nf)                          \
    _Pragma("unroll") for (int kk = 0; kk < 2; ++kk)                          \
      acc[(MB) + mf][(NB) + nf] = __builtin_amdgcn_mfma_i32_16x16x64_i8(      \
          afr[mf][kk], bfr[(NB) + nf][kk], acc[(MB) + mf][(NB) + nf], 0, 0, 0)

  // R5: no blanket lgkmcnt(0) — compiler emits per-MFMA counted lgkm waits,
  // overlapping the LDS drain with the MFMA cluster.
#define PHASE_MID()                                         \
    __builtin_amdgcn_s_barrier();                           \
    __builtin_amdgcn_s_setprio(1)

#define PHASE_END()                                         \
    __builtin_amdgcn_s_setprio(0);                          \
    __builtin_amdgcn_s_barrier()

  // ---- prologue: stage tiles 0 and 1 fully (16 loads); wait tile0 (vmcnt(8)) ----
  STAGE(gA,              lA,                 0);    // A(0) h0
  STAGE(gA + 128 * rowb, lA + 16384,         0);    // A(0) h1
  STAGE(gB,              lB,                 0);    // B(0) h0
  STAGE(gB + 128 * rowb, lB + 16384,         0);    // B(0) h1
  STAGE(gA,              lA + 32768,         128);  // A(1) h0
  STAGE(gA + 128 * rowb, lA + 32768 + 16384, 128);  // A(1) h1
  STAGE(gB,              lB + 32768,         128);  // B(1) h0
  STAGE(gB + 128 * rowb, lB + 32768 + 16384, 128);  // B(1) h1
  asm volatile("s_waitcnt vmcnt(8)" ::: "memory");  // tile0 landed; tile1 in flight
  __builtin_amdgcn_s_barrier();

#pragma unroll 2
  for (int t = 0; t < NT; ++t) {
    const int cur = (t & 1) * 32768;
    const size_t kN = (size_t)(t + 2) * 128;   // byte offset of K-tile t+2 (BK=128 i8)

    // ---------- phase 0 ----------
    __builtin_amdgcn_sched_barrier(0);
#pragma unroll
    for (int mf = 0; mf < 4; ++mf) { LDA(mf, 0, 0); LDA(mf, 0, 1); }
#pragma unroll
    for (int nf = 0; nf < 2; ++nf) { LDB(nf, 0); LDB(nf, 1); }
    PHASE_MID();
    QUAD(0, 0);
    PHASE_END();

    // ---------- phase 1 ----------
    __builtin_amdgcn_sched_barrier(0);
#pragma unroll
    for (int nf = 2; nf < 4; ++nf) { LDB(nf, 0); LDB(nf, 1); }
    PHASE_MID();
    QUAD(0, 2);
    PHASE_END();

    // ---------- phase 2 ----------
    __builtin_amdgcn_sched_barrier(0);
    if (t + 2 < NT) {                                   // B(t+2) -> cur (B-cur reads drained at ph1-end)
      STAGE(gB, lB + cur, kN);
      STAGE(gB + 128 * rowb, lB + cur + 16384, kN);
    }
#pragma unroll
    for (int mf = 0; mf < 4; ++mf) { LDA(mf, 4, 0); LDA(mf, 4, 1); }
    PHASE_MID();
    QUAD(4, 2);
    PHASE_END();

    // ---------- phase 3 ----------
    __builtin_amdgcn_sched_barrier(0);
    if (t + 2 < NT) {                                   // A(t+2) -> cur (A-cur reads drained at ph2-end)
      STAGE(gA, lA + cur, kN);
      STAGE(gA + 128 * rowb, lA + cur + 16384, kN);
    }
    PHASE_MID();
    QUAD(4, 0);
    __builtin_amdgcn_s_setprio(0);
    if (t < NT - 2) { asm volatile("s_waitcnt vmcnt(8)" ::: "memory"); }  // counted, never 0
    else           { asm volatile("s_waitcnt vmcnt(0)" ::: "memory"); }  // epilogue drain
    __builtin_amdgcn_s_barrier();
  }

  // ---- epilogue: C/D layout col = lane&15, row = (lane>>4)*4 + reg (dtype-independent) ----
  const int gr_base = trow * BM + wm * 128 + hi * 4;
  const int gc_base = tcol * BN + wn * 64 + lr;
  float sx[8][4];
#pragma unroll
  for (int mf = 0; mf < 8; ++mf)
#pragma unroll
    for (int j = 0; j < 4; ++j) sx[mf][j] = scale_x[gr_base + mf * 16 + j];
#pragma unroll
  for (int nf = 0; nf < 4; ++nf) {
    const int gc = gc_base + nf * 16;
    const float sw = scale_w[gc];
    const float bb = bias[gc];
#pragma unroll
    for (int mf = 0; mf < 8; ++mf) {
      const size_t rb = (size_t)(gr_base + mf * 16) * NOUT + gc;
#pragma unroll
      for (int j = 0; j < 4; ++j)
        out[rb + (size_t)j * NOUT] = (float)acc[mf][nf][j] * (sx[mf][j] * sw) + bb;
    }
  }
#undef STAGE
#undef LDA
#undef LDB
#undef QUAD
#undef PHASE_MID
#undef PHASE_END
}

extern "C" void kernel_launch(void* const* d_in, const int* in_sizes, int n_in,
                              void* d_out, int out_size, void* d_ws, size_t ws_size,
                              hipStream_t stream) {
  const float* X  = (const float*)d_in[0];   // [8192, 4096] fp32
  const float* W  = (const float*)d_in[1];   // [11008, 4096] fp32
  const float* Bi = (const float*)d_in[2];   // [11008] fp32
  float* out = (float*)d_out;                // [8192, 11008] fp32

  const size_t xq_bytes = (size_t)TOKENS * KIN;      // 32 MiB
  const size_t wq_bytes = (size_t)NOUT * KIN;        // 43 MiB
  const size_t need = xq_bytes + wq_bytes + (size_t)(NOUT + TOKENS) * sizeof(float);
  if (ws_size < need) return;  // needs ~76 MB scratch

  char* ws = (char*)d_ws;
  signed char* Xq = (signed char*)ws;
  signed char* Wq = (signed char*)(ws + xq_bytes);
  float* scale_w = (float*)(ws + xq_bytes + wq_bytes);
  float* scale_x = scale_w + NOUT;

  quant_weight_k<<<NOUT, 256, 0, stream>>>(W, Wq, scale_w);
  quant_input_k<<<TOKENS, 256, 0, stream>>>(X, Xq, scale_x);
  gemm_k<<<NWG, 512, 0, stream>>>(Xq, Wq, scale_x, scale_w, Bi, out);
}

// Round 6
// 446.437 us; speedup vs baseline: 1.6759x; 1.0426x over previous
//
#include <hip/hip_runtime.h>
#include <stdint.h>

#define TOKENS 8192
#define KIN    4096
#define NOUT   11008

// ---- 256x256 8-phase GEMM geometry (i8, BK=128 => 128 B/row) ----
#define BM 256
#define BN 256
#define BK 128
#define NT    (KIN / BK)      // 32 K-tiles
#define NTROW (TOKENS / BM)   // 32
#define NTCOL (NOUT / BN)     // 43
#define NWG   (NTROW * NTCOL) // 1376 = 8 XCDs x 172

using i32x4 = __attribute__((ext_vector_type(4))) int;

static __device__ __forceinline__ void gload_lds16(const void* g, void* l) {
  __builtin_amdgcn_global_load_lds((const __attribute__((address_space(1))) void*)g,
                                   (__attribute__((address_space(3))) void*)l,
                                   16, 0, 0);
}

static __device__ __forceinline__ int clamp_q(float f) {
  int q = (int)rintf(f);
  q = q > 127 ? 127 : q;
  q = q < -127 ? -127 : q;
  return q;
}

static __device__ __forceinline__ int pack4(int a, int b, int c, int d) {
  return (a & 0xff) | ((b & 0xff) << 8) | ((c & 0xff) << 16) | ((d & 0xff) << 24);
}

// ---- kernel 1: per-row absmean quantization: Wq = i8(round(W/scale)), scale_w[row] ----
__global__ __launch_bounds__(256) void quant_weight_k(const float* __restrict__ W,
                                                      signed char* __restrict__ Wq,
                                                      float* __restrict__ scale_w) {
  const int row = blockIdx.x;
  const int t   = threadIdx.x;
  const float4* wr = reinterpret_cast<const float4*>(W + (size_t)row * KIN);
  float4 v[4];
  double s = 0.0;
#pragma unroll
  for (int i = 0; i < 4; ++i) {
    v[i] = wr[t + i * 256];
    s += fabs((double)v[i].x) + fabs((double)v[i].y) +
         fabs((double)v[i].z) + fabs((double)v[i].w);
  }
#pragma unroll
  for (int off = 32; off > 0; off >>= 1) s += __shfl_down(s, off);
  __shared__ double red[4];
  if ((t & 63) == 0) red[t >> 6] = s;
  __syncthreads();
  const float sc = (float)((red[0] + red[1] + red[2] + red[3]) * (1.0 / KIN));
  if (t == 0) scale_w[row] = sc;
  int* qr = reinterpret_cast<int*>(Wq + (size_t)row * KIN);
#pragma unroll
  for (int i = 0; i < 4; ++i) {
    qr[t + i * 256] = pack4(clamp_q(v[i].x / sc), clamp_q(v[i].y / sc),
                            clamp_q(v[i].z / sc), clamp_q(v[i].w / sc));
  }
}

// ---- kernel 2: per-token symmetric i8 quantization of x: s_x = absmax/127 ----
__global__ __launch_bounds__(256) void quant_input_k(const float* __restrict__ X,
                                                     signed char* __restrict__ Xq,
                                                     float* __restrict__ scale_x) {
  const int row = blockIdx.x;
  const int t   = threadIdx.x;
  const float4* xr = reinterpret_cast<const float4*>(X + (size_t)row * KIN);
  float4 v[4];
  float amax = 0.f;
#pragma unroll
  for (int i = 0; i < 4; ++i) {
    v[i] = xr[t + i * 256];
    amax = fmaxf(amax, fmaxf(fmaxf(fabsf(v[i].x), fabsf(v[i].y)),
                             fmaxf(fabsf(v[i].z), fabsf(v[i].w))));
  }
#pragma unroll
  for (int off = 32; off > 0; off >>= 1) amax = fmaxf(amax, __shfl_down(amax, off));
  __shared__ float red[4];
  if ((t & 63) == 0) red[t >> 6] = amax;
  __syncthreads();
  amax = fmaxf(fmaxf(red[0], red[1]), fmaxf(red[2], red[3]));
  amax = fmaxf(amax, 1e-30f);
  const float inv = 127.0f / amax;
  if (t == 0) scale_x[row] = amax * (1.0f / 127.0f);
  int* qr = reinterpret_cast<int*>(Xq + (size_t)row * KIN);
#pragma unroll
  for (int i = 0; i < 4; ++i) {
    qr[t + i * 256] = pack4(clamp_q(v[i].x * inv), clamp_q(v[i].y * inv),
                            clamp_q(v[i].z * inv), clamp_q(v[i].w * inv));
  }
}

// ---- kernel 3: 256x256x128 i8 8-phase pipelined GEMM ----
// out[t,o] = s_x[t]*s_w[o]*(Xq[t,:].Wq[o,:])_i32 + bias[o].  Row-major [row][K] i8.
//
// R6 change: locality supertile swizzle. Diagnosis: FETCH_SIZE=747MB vs 75MB
// unique operands (10x HBM re-fetch) -> staging-bandwidth-bound (45% of cycles
// are vmcnt wait; R3 deeper prefetch + R5 lgkm overlap both null).
// New mapping: XCD x (= bid&7, dispatch round-robin) owns trow band [4x,4x+4);
// within the band, tiles iterate in 4trow x 4tcol chunks, so the 32 concurrent
// blocks per XCD form a 4x8 supertile: A = 4 panels (4MB, ~L2-resident all
// dispatch), B = 8 panels/round with 4-way concurrent sharing. Cuts per-round
// per-XCD unique traffic ~33MB -> 12MB.
__global__ __launch_bounds__(512, 2) void gemm_k(const signed char* __restrict__ Xq,
                                                 const signed char* __restrict__ Wq,
                                                 const float* __restrict__ scale_x,
                                                 const float* __restrict__ scale_w,
                                                 const float* __restrict__ bias,
                                                 float* __restrict__ out) {
  __shared__ alignas(16) char lds[131072];

  // ---- supertile swizzle: 1376 = 8 XCDs x 172; 172 = 10 full 4x4 chunks + 4x3 ----
  const int xcd = (int)blockIdx.x & 7;
  const int seq = (int)blockIdx.x >> 3;          // 0..171
  int trow, tcol;
  if (seq < 160) {
    const int chunk = seq >> 4;                  // 0..9
    const int rem   = seq & 15;
    trow = xcd * 4 + (rem >> 2);
    tcol = chunk * 4 + (rem & 3);
  } else {
    const int rem = seq - 160;                   // 0..11
    trow = xcd * 4 + rem / 3;
    tcol = 40 + rem % 3;
  }

  const int tid  = (int)threadIdx.x;
  const int lane = tid & 63;
  const int wave = tid >> 6;   // 0..7
  const int wm   = wave >> 2;  // 0..1 : M half (128 rows)
  const int wn   = wave & 3;   // 0..3 : N quarter (64 cols)

  // ---- staging lane addresses (inverse-swizzled global source, linear LDS dest) ----
  const int l8 = lane >> 3;                          // row within 8-row group
  const size_t rowb = (size_t)KIN;                   // 4096 B per row (i8)
  const int swzl = ((lane & 7) ^ l8) * 16;           // pre-swizzled slot within 128-B row chunk
  const char* gA = (const char*)Xq + (size_t)(trow * BM + wave * 16 + l8) * rowb + swzl;
  const char* gB = (const char*)Wq + (size_t)(tcol * BN + wave * 16 + l8) * rowb + swzl;
  char* lA = lds + wave * 2048;            // + buf*32768 + h*16384 (+1024 for 2nd gload)
  char* lB = lds + 65536 + wave * 2048;

#define STAGE(gp, lp, koff) do {                                             \
    gload_lds16((gp) + (koff), (lp));                                        \
    gload_lds16((gp) + (koff) + (size_t)(8 * 4096), (char*)(lp) + 1024);     \
  } while (0)

  // ---- ds_read bases (swizzled) ----
  const int lr = lane & 15;
  const int hi = lane >> 4;                          // 0..3 -> k-slot within 64-B k-slice
  const int swz0 = (hi * 16) ^ ((lr & 7) << 4);
  const int swz[2] = { swz0, swz0 ^ 64 };            // ks=0 / ks=1 (XOR: bit6 overlaps swizzle field)
  const char* rdA = lds + wm * 16384 + lr * 128;
  const char* rdB = lds + 65536 + (wn >> 1) * 16384 + ((wn & 1) * 64 + lr) * 128;

  i32x4 acc[8][4];
#pragma unroll
  for (int m = 0; m < 8; ++m)
#pragma unroll
    for (int n = 0; n < 4; ++n) acc[m][n] = (i32x4){0, 0, 0, 0};
  i32x4 afr[4][2], bfr[4][2];

#define LDA(mf, mbase, kk) afr[mf][kk] = *(const i32x4*)(rdA + cur + ((mbase) + (mf)) * 2048 + swz[kk])
#define LDB(nf, kk)        bfr[nf][kk] = *(const i32x4*)(rdB + cur + (nf) * 2048 + swz[kk])

#define QUAD(MB, NB)                                                          \
    _Pragma("unroll") for (int mf = 0; mf < 4; ++mf)                          \
    _Pragma("unroll") for (int nf = 0; nf < 2; ++nf)                          \
    _Pragma("unroll") for (int kk = 0; kk < 2; ++kk)                          \
      acc[(MB) + mf][(NB) + nf] = __builtin_amdgcn_mfma_i32_16x16x64_i8(      \
          afr[mf][kk], bfr[(NB) + nf][kk], acc[(MB) + mf][(NB) + nf], 0, 0, 0)

#define PHASE_MID()                                         \
    __builtin_amdgcn_s_barrier();                           \
    __builtin_amdgcn_s_setprio(1)

#define PHASE_END()                                         \
    __builtin_amdgcn_s_setprio(0);                          \
    __builtin_amdgcn_s_barrier()

  // ---- prologue: stage tiles 0 and 1 fully (16 loads); wait tile0 (vmcnt(8)) ----
  STAGE(gA,              lA,                 0);    // A(0) h0
  STAGE(gA + 128 * rowb, lA + 16384,         0);    // A(0) h1
  STAGE(gB,              lB,                 0);    // B(0) h0
  STAGE(gB + 128 * rowb, lB + 16384,         0);    // B(0) h1
  STAGE(gA,              lA + 32768,         128);  // A(1) h0
  STAGE(gA + 128 * rowb, lA + 32768 + 16384, 128);  // A(1) h1
  STAGE(gB,              lB + 32768,         128);  // B(1) h0
  STAGE(gB + 128 * rowb, lB + 32768 + 16384, 128);  // B(1) h1
  asm volatile("s_waitcnt vmcnt(8)" ::: "memory");  // tile0 landed; tile1 in flight
  __builtin_amdgcn_s_barrier();

#pragma unroll 2
  for (int t = 0; t < NT; ++t) {
    const int cur = (t & 1) * 32768;
    const size_t kN = (size_t)(t + 2) * 128;   // byte offset of K-tile t+2 (BK=128 i8)

    // ---------- phase 0 ----------
    __builtin_amdgcn_sched_barrier(0);
#pragma unroll
    for (int mf = 0; mf < 4; ++mf) { LDA(mf, 0, 0); LDA(mf, 0, 1); }
#pragma unroll
    for (int nf = 0; nf < 2; ++nf) { LDB(nf, 0); LDB(nf, 1); }
    PHASE_MID();
    QUAD(0, 0);
    PHASE_END();

    // ---------- phase 1 ----------
    __builtin_amdgcn_sched_barrier(0);
#pragma unroll
    for (int nf = 2; nf < 4; ++nf) { LDB(nf, 0); LDB(nf, 1); }
    PHASE_MID();
    QUAD(0, 2);
    PHASE_END();

    // ---------- phase 2 ----------
    __builtin_amdgcn_sched_barrier(0);
    if (t + 2 < NT) {                                   // B(t+2) -> cur (B-cur reads drained at ph1-end)
      STAGE(gB, lB + cur, kN);
      STAGE(gB + 128 * rowb, lB + cur + 16384, kN);
    }
#pragma unroll
    for (int mf = 0; mf < 4; ++mf) { LDA(mf, 4, 0); LDA(mf, 4, 1); }
    PHASE_MID();
    QUAD(4, 2);
    PHASE_END();

    // ---------- phase 3 ----------
    __builtin_amdgcn_sched_barrier(0);
    if (t + 2 < NT) {                                   // A(t+2) -> cur (A-cur reads drained at ph2-end)
      STAGE(gA, lA + cur, kN);
      STAGE(gA + 128 * rowb, lA + cur + 16384, kN);
    }
    PHASE_MID();
    QUAD(4, 0);
    __builtin_amdgcn_s_setprio(0);
    if (t < NT - 2) { asm volatile("s_waitcnt vmcnt(8)" ::: "memory"); }  // counted, never 0
    else           { asm volatile("s_waitcnt vmcnt(0)" ::: "memory"); }  // epilogue drain
    __builtin_amdgcn_s_barrier();
  }

  // ---- epilogue: C/D layout col = lane&15, row = (lane>>4)*4 + reg (dtype-independent) ----
  // Nontemporal: write-once output; reduce L3 write-allocation pressure so
  // operand panels stay resident (mechanism now active with supertile locality).
  const int gr_base = trow * BM + wm * 128 + hi * 4;
  const int gc_base = tcol * BN + wn * 64 + lr;
  float sx[8][4];
#pragma unroll
  for (int mf = 0; mf < 8; ++mf)
#pragma unroll
    for (int j = 0; j < 4; ++j) sx[mf][j] = scale_x[gr_base + mf * 16 + j];
#pragma unroll
  for (int nf = 0; nf < 4; ++nf) {
    const int gc = gc_base + nf * 16;
    const float sw = scale_w[gc];
    const float bb = bias[gc];
#pragma unroll
    for (int mf = 0; mf < 8; ++mf) {
      const size_t rb = (size_t)(gr_base + mf * 16) * NOUT + gc;
#pragma unroll
      for (int j = 0; j < 4; ++j)
        __builtin_nontemporal_store((float)acc[mf][nf][j] * (sx[mf][j] * sw) + bb,
                                    &out[rb + (size_t)j * NOUT]);
    }
  }
#undef STAGE
#undef LDA
#undef LDB
#undef QUAD
#undef PHASE_MID
#undef PHASE_END
}

extern "C" void kernel_launch(void* const* d_in, const int* in_sizes, int n_in,
                              void* d_out, int out_size, void* d_ws, size_t ws_size,
                              hipStream_t stream) {
  const float* X  = (const float*)d_in[0];   // [8192, 4096] fp32
  const float* W  = (const float*)d_in[1];   // [11008, 4096] fp32
  const float* Bi = (const float*)d_in[2];   // [11008] fp32
  float* out = (float*)d_out;                // [8192, 11008] fp32

  const size_t xq_bytes = (size_t)TOKENS * KIN;      // 32 MiB
  const size_t wq_bytes = (size_t)NOUT * KIN;        // 43 MiB
  const size_t need = xq_bytes + wq_bytes + (size_t)(NOUT + TOKENS) * sizeof(float);
  if (ws_size < need) return;  // needs ~76 MB scratch

  char* ws = (char*)d_ws;
  signed char* Xq = (signed char*)ws;
  signed char* Wq = (signed char*)(ws + xq_bytes);
  float* scale_w = (float*)(ws + xq_bytes + wq_bytes);
  float* scale_x = scale_w + NOUT;

  quant_weight_k<<<NOUT, 256, 0, stream>>>(W, Wq, scale_w);
  quant_input_k<<<TOKENS, 256, 0, stream>>>(X, Xq, scale_x);
  gemm_k<<<NWG, 512, 0, stream>>>(Xq, Wq, scale_x, scale_w, Bi, out);
}